// Round 16
// baseline (149.873 us; speedup 1.0000x reference)
//
#include <hip/hip_runtime.h>

// RGCN on MI355X. Algebra: mean-aggregate x per (relation,dst) FIRST (linearity
// of mean), then one fused [N,640]@[640,128] bf16 MFMA GEMM per layer.
// R16: exactly R13 (best known, 138.8us) + ONE change: nontemporal xcat stores
//     in k_agg (isolated test of the L3-eviction theory; R8's NT test was
//     confounded with MLP-8 and XCD-partitioned hist).

#define N_NODES 50000
#define N_EDGES 800000
#define N_REL 4
#define DIM 128
#define NPAD 50048              // 782 * 64 (GEMM BM=64 tiles)
#define RN (N_REL * N_NODES)    // 200000 buckets, key = dst*4 + et
#define CAP 32                  // logical bucket capacity (8 main + 24 overflow)
#define OVF 24

#define NBIN 391                // coarse bins: dst>>7 (128 dst per bin)
#define BINCAP 3072             // per-bin buffer capacity (mean 2046, 22-sigma safe)

// pass A grid partition (1024-thread blocks)
#define BIN_B 196               // 196*4096 >= 800000 edges, 4/thread
#define XCAST_B 782             // 800000 8-elem chunks / 1024
#define WPREP_B 160             // 2*128*640 / 1024
#define PREPA_B (BIN_B + XCAST_B + WPREP_B)

typedef __bf16 bf16x8 __attribute__((ext_vector_type(8)));
typedef float f32x4 __attribute__((ext_vector_type(4)));
typedef float f32x2 __attribute__((ext_vector_type(2)));
typedef unsigned int u32x4 __attribute__((ext_vector_type(4)));

__device__ __forceinline__ unsigned short f2bf(float f) {
    unsigned u = __builtin_bit_cast(unsigned, f);
    u += 0x7FFFu + ((u >> 16) & 1u);       // round-to-nearest-even
    return (unsigned short)(u >> 16);
}

__device__ __forceinline__ unsigned cvt_pk_bf16(float lo, float hi) {
    unsigned r;
    asm("v_cvt_pk_bf16_f32 %0, %1, %2" : "=v"(r) : "v"(lo), "v"(hi));
    return r;
}

__device__ __forceinline__ void pk_add(f32x2& acc, f32x2 v) {
    asm("v_pk_add_f32 %0, %1, %0" : "+v"(acc) : "v"(v));
}

// accumulate one 16B chunk (8 bf16) into 4 packed f32 pairs
__device__ __forceinline__ void acc_row(f32x2* acc, uint4 d) {
#pragma unroll
    for (int k = 0; k < 4; k++) {
        unsigned dw = (&d.x)[k];
        f32x2 v;
        v[0] = __builtin_bit_cast(float, dw << 16);
        v[1] = __builtin_bit_cast(float, dw & 0xFFFF0000u);
        pk_add(acc[k], v);
    }
}

__device__ __forceinline__ void gload_lds16(const void* g, void* lds) {
    __builtin_amdgcn_global_load_lds(
        (const __attribute__((address_space(1))) void*)g,
        (__attribute__((address_space(3))) void*)lds, 16, 0, 0);
}

// ---------- zero the 512-dword gbincnt ----------
__global__ __launch_bounds__(512) void k_zero(unsigned* __restrict__ g) {
    g[threadIdx.x] = 0u;
}

// ---------- pass A: coarse bin (LDS hist) | xcast | wprep ----------
// packed edge word: src[15:0] | dstlo[22:16] | et[24:23]
__global__ __launch_bounds__(1024) void k_prepA(const int* __restrict__ et,
                                                const int* __restrict__ dst,
                                                const int* __restrict__ src,
                                                unsigned* __restrict__ gbincnt,
                                                unsigned* __restrict__ binbuf,
                                                const float* __restrict__ X,
                                                unsigned short* __restrict__ Xb,
                                                const float* __restrict__ weights,
                                                const float* __restrict__ roots,
                                                unsigned short* __restrict__ wcatT) {
    __shared__ int lcnt[NBIN];
    __shared__ int lbase[NBIN];
    const int blk = blockIdx.x, tid = threadIdx.x;
    if (blk < BIN_B) {
        if (tid < NBIN) lcnt[tid] = 0;
        __syncthreads();
        int base = blk * 4096 + tid * 4;
        int bin[4], lr[4];
        unsigned pack[4];
        int ne = 0;
        if (base + 3 < N_EDGES) {
            int4 e4 = *(const int4*)(et + base);
            int4 d4 = *(const int4*)(dst + base);
            int4 s4 = *(const int4*)(src + base);
            ne = 4;
#pragma unroll
            for (int k = 0; k < 4; k++) {
                int d = (&d4.x)[k];
                bin[k] = d >> 7;
                pack[k] = (unsigned)(&s4.x)[k] | ((unsigned)(d & 127) << 16) |
                          ((unsigned)(&e4.x)[k] << 23);
                lr[k] = atomicAdd(&lcnt[bin[k]], 1);
            }
        } else {
            for (int k = 0; k < 4; k++) {
                int i = base + k;
                if (i < N_EDGES) {
                    int d = dst[i];
                    bin[ne] = d >> 7;
                    pack[ne] = (unsigned)src[i] | ((unsigned)(d & 127) << 16) |
                               ((unsigned)et[i] << 23);
                    lr[ne] = atomicAdd(&lcnt[bin[ne]], 1);
                    ne++;
                }
            }
        }
        __syncthreads();
        if (tid < NBIN) {
            int c = lcnt[tid];
            lbase[tid] = c ? (int)atomicAdd(&gbincnt[tid], (unsigned)c) : 0;
        }
        __syncthreads();
        for (int k = 0; k < ne; k++) {
            int pos = lbase[bin[k]] + lr[k];
            if (pos < BINCAP) binbuf[(size_t)bin[k] * BINCAP + pos] = pack[k];
        }
    } else if (blk < BIN_B + XCAST_B) {
        int i = (blk - BIN_B) * 1024 + tid;          // one thread = 8 elems
        if (i < N_NODES * DIM / 8) {
            f32x4 a = *(const f32x4*)(X + (size_t)i * 8);
            f32x4 b = *(const f32x4*)(X + (size_t)i * 8 + 4);
            u32x4 o;
            o.x = cvt_pk_bf16(a[0], a[1]);
            o.y = cvt_pk_bf16(a[2], a[3]);
            o.z = cvt_pk_bf16(b[0], b[1]);
            o.w = cvt_pk_bf16(b[2], b[3]);
            *(u32x4*)(Xb + (size_t)i * 8) = o;
        }
    } else {
        int idx = (blk - BIN_B - XCAST_B) * 1024 + tid;
        int k = idx % 640;
        int n = (idx / 640) % 128;
        int l = idx / (640 * 128);
        float v;
        if (k < 128) {
            v = roots[(l * 128 + k) * 128 + n];
        } else {
            int r = (k - 128) >> 7;
            int kk = (k - 128) & 127;
            v = weights[((l * N_REL + r) * 128 + kk) * 128 + n];
        }
        wcatT[idx] = f2bf(v);
    }
}

// ---------- pass B: per-bin fine CSR build (LDS atomics only) ----------
__global__ __launch_bounds__(1024) void k_fine(const unsigned* __restrict__ gbincnt,
                                               const unsigned* __restrict__ binbuf,
                                               unsigned char* __restrict__ cnt8,
                                               unsigned short* __restrict__ elist8,
                                               unsigned short* __restrict__ ovf) {
    __shared__ int lcnt[512];
    const int b = blockIdx.x, tid = threadIdx.x;
    if (tid < 512) lcnt[tid] = 0;
    __syncthreads();
    int n = (int)gbincnt[b];
    n = (n > BINCAP) ? BINCAP : n;
    const unsigned* bb = binbuf + (size_t)b * BINCAP;
    const int rn0 = b * 512;
    for (int j = tid; j < n; j += 1024) {
        unsigned w = bb[j];
        int bl = (int)(((w >> 16) & 127) << 2) | (int)((w >> 23) & 3);
        int lr = atomicAdd(&lcnt[bl], 1);
        int rn = rn0 + bl;
        if (lr < 8) {
            elist8[(size_t)rn * 8 + lr] = (unsigned short)(w & 0xFFFF);
        } else if (lr < CAP) {
            ovf[(size_t)rn * OVF + (lr - 8)] = (unsigned short)(w & 0xFFFF);
        }
    }
    __syncthreads();
    if (tid < 512) {
        int rn = rn0 + tid;
        if (rn < RN) {
            int c = lcnt[tid];
            cnt8[rn] = (unsigned char)((c > 255) ? 255 : c);
        }
    }
}

// ---------- aggregate: wave = node, 16-lane group g = relation g (MLP-4) ----------
// preload 8 indices as uint4 (== elist8[bucket]); 4 guarded gathers in flight;
// rare tail from overflow. xcat row = [mean_r0..mean_r3] (512 cols bf16)
// R16: xcat stores are nontemporal (keep feature table L2/L3-resident).
__global__ __launch_bounds__(256) void k_agg(const unsigned short* __restrict__ Xb,
                                             const unsigned char* __restrict__ cnt8,
                                             const unsigned short* __restrict__ elist8,
                                             const unsigned short* __restrict__ ovf,
                                             unsigned short* __restrict__ xcat) {
    int node = blockIdx.x * 4 + (threadIdx.x >> 6);
    int lane = threadIdx.x & 63;
    const int g = lane >> 4;     // relation
    const int t = lane & 15;     // lane-in-group: owns cols t*8..t*8+7 of that relation

    int bucket = (node << 2) | g;
    int c = cnt8[bucket];
    c = (c > CAP) ? CAP : c;
    uint4 e8 = *(const uint4*)(elist8 + (size_t)bucket * 8);   // entries 0..7

    int i0 = e8.x & 0xFFFF, i1 = e8.x >> 16;
    int i2 = e8.y & 0xFFFF, i3 = e8.y >> 16;
    int i4 = e8.z & 0xFFFF, i5 = e8.z >> 16;
    int i6 = e8.w & 0xFFFF, i7 = e8.w >> 16;

    const size_t toff = (size_t)(t * 8);
    const uint4 z = {0, 0, 0, 0};
    f32x2 A0[4] = {}, A1[4] = {}, A2[4] = {}, A3[4] = {};

    // chunk 0: edges 0..3, 4 loads in flight
    {
        uint4 d0 = z, d1 = z, d2 = z, d3 = z;
        if (c > 0) d0 = *(const uint4*)(Xb + (size_t)i0 * DIM + toff);
        if (c > 1) d1 = *(const uint4*)(Xb + (size_t)i1 * DIM + toff);
        if (c > 2) d2 = *(const uint4*)(Xb + (size_t)i2 * DIM + toff);
        if (c > 3) d3 = *(const uint4*)(Xb + (size_t)i3 * DIM + toff);
        acc_row(A0, d0); acc_row(A1, d1); acc_row(A2, d2); acc_row(A3, d3);
    }
    // chunk 1: edges 4..7
    if (c > 4) {
        uint4 d0 = z, d1 = z, d2 = z, d3 = z;
        d0 = *(const uint4*)(Xb + (size_t)i4 * DIM + toff);
        if (c > 5) d1 = *(const uint4*)(Xb + (size_t)i5 * DIM + toff);
        if (c > 6) d2 = *(const uint4*)(Xb + (size_t)i6 * DIM + toff);
        if (c > 7) d3 = *(const uint4*)(Xb + (size_t)i7 * DIM + toff);
        acc_row(A0, d0); acc_row(A1, d1); acc_row(A2, d2); acc_row(A3, d3);
    }
    // rare tail (P(c>8) ~ 2%) from overflow region
    for (int j = 8; j < c; ++j) {
        int s = ovf[(size_t)bucket * OVF + (j - 8)];
        uint4 d = *(const uint4*)(Xb + (size_t)s * DIM + toff);
        acc_row(A0, d);
    }
#pragma unroll
    for (int k = 0; k < 4; k++) {
        pk_add(A0[k], A1[k]);
        pk_add(A2[k], A3[k]);
        pk_add(A0[k], A2[k]);
    }

    float inv = 1.0f / fmaxf((float)c, 1.0f);
    u32x4 o;
    o.x = cvt_pk_bf16(A0[0][0] * inv, A0[0][1] * inv);
    o.y = cvt_pk_bf16(A0[1][0] * inv, A0[1][1] * inv);
    o.z = cvt_pk_bf16(A0[2][0] * inv, A0[2][1] * inv);
    o.w = cvt_pk_bf16(A0[3][0] * inv, A0[3][1] * inv);
    __builtin_nontemporal_store(o, (u32x4*)(xcat + (size_t)node * 512 + g * 128 + t * 8));
}

// ---------- GEMM: Y[M,128] = [Xself | xcat][M,640](bf16) @ wcatT[128][640](bf16) ----------
// BM=64, BN=128, BK=64; 4 waves (2x2), each wave 32x64 out; 16x16x32 MFMA.
// A K-tiles 0..1 staged from Xself (stride 256B), 2..9 from xcat (stride 1024B).
__global__ __launch_bounds__(256) void k_gemm(const unsigned short* __restrict__ Xself,
                                              const unsigned short* __restrict__ Xagg,
                                              const unsigned short* __restrict__ Bt,
                                              const float* __restrict__ bias,
                                              void* __restrict__ Yv, int Mout,
                                              int relu, int obf16) {
    __shared__ unsigned short sA[64 * 64];    // [row][64 k] bf16, 16B-chunk XOR swizzled
    __shared__ unsigned short sB[128 * 64];   // [n][64 k]

    const int tid = threadIdx.x;
    const int lane = tid & 63;
    const int wid = tid >> 6;
    const int wm = wid >> 1, wn = wid & 1;
    const int m0 = blockIdx.x * 64;

    f32x4 acc[2][4] = {};

    const char* Bbase = (const char*)Bt;

    for (int kt = 0; kt < 10; ++kt) {
        const char* Asrc;
        size_t rstride;
        if (kt < 2) {
            Asrc = (const char*)Xself + (size_t)m0 * 256 + kt * 128;
            rstride = 256;
        } else {
            Asrc = (const char*)Xagg + (size_t)m0 * 1024 + (kt - 2) * 128;
            rstride = 1024;
        }
#pragma unroll
        for (int i = 0; i < 2; i++) {
            int chunk = i * 256 + tid;
            int row = chunk >> 3, cst = chunk & 7;
            int clog = cst ^ (row & 7);
            gload_lds16(Asrc + (size_t)row * rstride + clog * 16,
                        (char*)sA + (size_t)(chunk - lane) * 16);
        }
#pragma unroll
        for (int i = 0; i < 4; i++) {
            int chunk = i * 256 + tid;
            int row = chunk >> 3, cst = chunk & 7;
            int clog = cst ^ (row & 7);
            gload_lds16(Bbase + (size_t)row * 1280 + kt * 128 + clog * 16,
                        (char*)sB + (size_t)(chunk - lane) * 16);
        }
        __syncthreads();
#pragma unroll
        for (int ki = 0; ki < 2; ki++) {
            bf16x8 a[2], b[4];
#pragma unroll
            for (int mi = 0; mi < 2; mi++) {
                int row = wm * 32 + mi * 16 + (lane & 15);
                int c = ki * 4 + (lane >> 4);
                a[mi] = *(const bf16x8*)((const char*)sA + row * 128 + ((c ^ (row & 7)) << 4));
            }
#pragma unroll
            for (int ni = 0; ni < 4; ni++) {
                int row = wn * 64 + ni * 16 + (lane & 15);
                int c = ki * 4 + (lane >> 4);
                b[ni] = *(const bf16x8*)((const char*)sB + row * 128 + ((c ^ (row & 7)) << 4));
            }
#pragma unroll
            for (int mi = 0; mi < 2; mi++)
#pragma unroll
                for (int ni = 0; ni < 4; ni++)
                    acc[mi][ni] = __builtin_amdgcn_mfma_f32_16x16x32_bf16(a[mi], b[ni], acc[mi][ni], 0, 0, 0);
        }
        __syncthreads();
    }
#pragma unroll
    for (int mi = 0; mi < 2; mi++) {
#pragma unroll
        for (int ni = 0; ni < 4; ni++) {
            int col = wn * 64 + ni * 16 + (lane & 15);
            float bv = bias[col];
#pragma unroll
            for (int q = 0; q < 4; q++) {
                int row = m0 + wm * 32 + mi * 16 + (lane >> 4) * 4 + q;
                if (row < Mout) {
                    float v = acc[mi][ni][q] + bv;
                    if (relu) v = fmaxf(v, 0.f);
                    if (obf16)
                        ((unsigned short*)Yv)[(size_t)row * DIM + col] = f2bf(v);
                    else
                        ((float*)Yv)[(size_t)row * DIM + col] = v;
                }
            }
        }
    }
}

extern "C" void kernel_launch(void* const* d_in, const int* in_sizes, int n_in,
                              void* d_out, int out_size, void* d_ws, size_t ws_size,
                              hipStream_t stream) {
    const float* x = (const float*)d_in[0];
    const int* ei = (const int*)d_in[1];      // [2,E]: src = ei, dst = ei+E
    const int* et = (const int*)d_in[2];      // [E]
    const float* weights = (const float*)d_in[3];  // [L,R,D,D]
    const float* roots = (const float*)d_in[4];    // [L,D,D]
    const float* biases = (const float*)d_in[5];   // [L,D]
    float* out = (float*)d_out;

    const int* src = ei;
    const int* dst = ei + N_EDGES;

    // workspace layout (~95 MB)
    unsigned* gbincnt = (unsigned*)d_ws;                          // 512 u32
    unsigned* binbuf = gbincnt + 512;                             // NBIN*BINCAP u32 = 4.8 MB
    unsigned char* cnt8 = (unsigned char*)(binbuf + (size_t)NBIN * BINCAP);  // 200192 B
    unsigned short* elist8 = (unsigned short*)(cnt8 + 200192);    // RN*8 u16 = 3.2 MB
    unsigned short* ovf = elist8 + (size_t)RN * 8;                // RN*OVF u16 = 9.6 MB
    unsigned short* wcatT = ovf + (size_t)RN * OVF;               // 2*128*640
    unsigned short* xcat = wcatT + 2 * 128 * 640;                 // NPAD*512 bf16 = 51.2 MB
    unsigned short* xb = xcat + (size_t)NPAD * 512;               // NPAD*128 bf16
    unsigned short* hb = xb + (size_t)NPAD * 128;                 // NPAD*128 bf16

    k_zero<<<1, 512, 0, stream>>>(gbincnt);

    k_prepA<<<PREPA_B, 1024, 0, stream>>>(et, dst, src, gbincnt, binbuf, x, xb,
                                          weights, roots, wcatT);
    k_fine<<<NBIN, 1024, 0, stream>>>(gbincnt, binbuf, cnt8, elist8, ovf);

    // layer 0: xb -> hb (ReLU, bf16 out)
    k_agg<<<N_NODES / 4, 256, 0, stream>>>(xb, cnt8, elist8, ovf, xcat);
    k_gemm<<<NPAD / 64, 256, 0, stream>>>(xb, xcat, wcatT, biases, hb, N_NODES, 1, 1);
    // layer 1: hb -> out (no ReLU, fp32 out)
    k_agg<<<N_NODES / 4, 256, 0, stream>>>(hb, cnt8, elist8, ovf, xcat);
    k_gemm<<<NPAD / 64, 256, 0, stream>>>(hb, xcat, wcatT + 128 * 640, biases + DIM, out, N_NODES, 0, 0);
}

// Round 17
// 138.635 us; speedup vs baseline: 1.0811x; 1.0811x over previous
//
#include <hip/hip_runtime.h>

// RGCN on MI355X. Algebra: mean-aggregate x per (relation,dst) FIRST (linearity
// of mean), then one fused [N,640]@[640,128] bf16 MFMA GEMM per layer.
// R17: byte-identical revert to R13 (best known: 138.8us). NT-store (R16),
//     NT-load (R15), MLP-8 (R14), all falsified. This structure's accounting
//     (2x38 agg gather floor + 2x11 gemm + 23 prep + ~12 launch) matches the
//     measurement — roofline for this decomposition.

#define N_NODES 50000
#define N_EDGES 800000
#define N_REL 4
#define DIM 128
#define NPAD 50048              // 782 * 64 (GEMM BM=64 tiles)
#define RN (N_REL * N_NODES)    // 200000 buckets, key = dst*4 + et
#define CAP 32                  // logical bucket capacity (8 main + 24 overflow)
#define OVF 24

#define NBIN 391                // coarse bins: dst>>7 (128 dst per bin)
#define BINCAP 3072             // per-bin buffer capacity (mean 2046, 22-sigma safe)

// pass A grid partition (1024-thread blocks)
#define BIN_B 196               // 196*4096 >= 800000 edges, 4/thread
#define XCAST_B 782             // 800000 8-elem chunks / 1024
#define WPREP_B 160             // 2*128*640 / 1024
#define PREPA_B (BIN_B + XCAST_B + WPREP_B)

typedef __bf16 bf16x8 __attribute__((ext_vector_type(8)));
typedef float f32x4 __attribute__((ext_vector_type(4)));
typedef float f32x2 __attribute__((ext_vector_type(2)));
typedef unsigned int u32x4 __attribute__((ext_vector_type(4)));

__device__ __forceinline__ unsigned short f2bf(float f) {
    unsigned u = __builtin_bit_cast(unsigned, f);
    u += 0x7FFFu + ((u >> 16) & 1u);       // round-to-nearest-even
    return (unsigned short)(u >> 16);
}

__device__ __forceinline__ unsigned cvt_pk_bf16(float lo, float hi) {
    unsigned r;
    asm("v_cvt_pk_bf16_f32 %0, %1, %2" : "=v"(r) : "v"(lo), "v"(hi));
    return r;
}

__device__ __forceinline__ void pk_add(f32x2& acc, f32x2 v) {
    asm("v_pk_add_f32 %0, %1, %0" : "+v"(acc) : "v"(v));
}

// accumulate one 16B chunk (8 bf16) into 4 packed f32 pairs
__device__ __forceinline__ void acc_row(f32x2* acc, uint4 d) {
#pragma unroll
    for (int k = 0; k < 4; k++) {
        unsigned dw = (&d.x)[k];
        f32x2 v;
        v[0] = __builtin_bit_cast(float, dw << 16);
        v[1] = __builtin_bit_cast(float, dw & 0xFFFF0000u);
        pk_add(acc[k], v);
    }
}

__device__ __forceinline__ void gload_lds16(const void* g, void* lds) {
    __builtin_amdgcn_global_load_lds(
        (const __attribute__((address_space(1))) void*)g,
        (__attribute__((address_space(3))) void*)lds, 16, 0, 0);
}

// ---------- zero the 512-dword gbincnt ----------
__global__ __launch_bounds__(512) void k_zero(unsigned* __restrict__ g) {
    g[threadIdx.x] = 0u;
}

// ---------- pass A: coarse bin (LDS hist) | xcast | wprep ----------
// packed edge word: src[15:0] | dstlo[22:16] | et[24:23]
__global__ __launch_bounds__(1024) void k_prepA(const int* __restrict__ et,
                                                const int* __restrict__ dst,
                                                const int* __restrict__ src,
                                                unsigned* __restrict__ gbincnt,
                                                unsigned* __restrict__ binbuf,
                                                const float* __restrict__ X,
                                                unsigned short* __restrict__ Xb,
                                                const float* __restrict__ weights,
                                                const float* __restrict__ roots,
                                                unsigned short* __restrict__ wcatT) {
    __shared__ int lcnt[NBIN];
    __shared__ int lbase[NBIN];
    const int blk = blockIdx.x, tid = threadIdx.x;
    if (blk < BIN_B) {
        if (tid < NBIN) lcnt[tid] = 0;
        __syncthreads();
        int base = blk * 4096 + tid * 4;
        int bin[4], lr[4];
        unsigned pack[4];
        int ne = 0;
        if (base + 3 < N_EDGES) {
            int4 e4 = *(const int4*)(et + base);
            int4 d4 = *(const int4*)(dst + base);
            int4 s4 = *(const int4*)(src + base);
            ne = 4;
#pragma unroll
            for (int k = 0; k < 4; k++) {
                int d = (&d4.x)[k];
                bin[k] = d >> 7;
                pack[k] = (unsigned)(&s4.x)[k] | ((unsigned)(d & 127) << 16) |
                          ((unsigned)(&e4.x)[k] << 23);
                lr[k] = atomicAdd(&lcnt[bin[k]], 1);
            }
        } else {
            for (int k = 0; k < 4; k++) {
                int i = base + k;
                if (i < N_EDGES) {
                    int d = dst[i];
                    bin[ne] = d >> 7;
                    pack[ne] = (unsigned)src[i] | ((unsigned)(d & 127) << 16) |
                               ((unsigned)et[i] << 23);
                    lr[ne] = atomicAdd(&lcnt[bin[ne]], 1);
                    ne++;
                }
            }
        }
        __syncthreads();
        if (tid < NBIN) {
            int c = lcnt[tid];
            lbase[tid] = c ? (int)atomicAdd(&gbincnt[tid], (unsigned)c) : 0;
        }
        __syncthreads();
        for (int k = 0; k < ne; k++) {
            int pos = lbase[bin[k]] + lr[k];
            if (pos < BINCAP) binbuf[(size_t)bin[k] * BINCAP + pos] = pack[k];
        }
    } else if (blk < BIN_B + XCAST_B) {
        int i = (blk - BIN_B) * 1024 + tid;          // one thread = 8 elems
        if (i < N_NODES * DIM / 8) {
            f32x4 a = *(const f32x4*)(X + (size_t)i * 8);
            f32x4 b = *(const f32x4*)(X + (size_t)i * 8 + 4);
            u32x4 o;
            o.x = cvt_pk_bf16(a[0], a[1]);
            o.y = cvt_pk_bf16(a[2], a[3]);
            o.z = cvt_pk_bf16(b[0], b[1]);
            o.w = cvt_pk_bf16(b[2], b[3]);
            *(u32x4*)(Xb + (size_t)i * 8) = o;
        }
    } else {
        int idx = (blk - BIN_B - XCAST_B) * 1024 + tid;
        int k = idx % 640;
        int n = (idx / 640) % 128;
        int l = idx / (640 * 128);
        float v;
        if (k < 128) {
            v = roots[(l * 128 + k) * 128 + n];
        } else {
            int r = (k - 128) >> 7;
            int kk = (k - 128) & 127;
            v = weights[((l * N_REL + r) * 128 + kk) * 128 + n];
        }
        wcatT[idx] = f2bf(v);
    }
}

// ---------- pass B: per-bin fine CSR build (LDS atomics only) ----------
__global__ __launch_bounds__(1024) void k_fine(const unsigned* __restrict__ gbincnt,
                                               const unsigned* __restrict__ binbuf,
                                               unsigned char* __restrict__ cnt8,
                                               unsigned short* __restrict__ elist8,
                                               unsigned short* __restrict__ ovf) {
    __shared__ int lcnt[512];
    const int b = blockIdx.x, tid = threadIdx.x;
    if (tid < 512) lcnt[tid] = 0;
    __syncthreads();
    int n = (int)gbincnt[b];
    n = (n > BINCAP) ? BINCAP : n;
    const unsigned* bb = binbuf + (size_t)b * BINCAP;
    const int rn0 = b * 512;
    for (int j = tid; j < n; j += 1024) {
        unsigned w = bb[j];
        int bl = (int)(((w >> 16) & 127) << 2) | (int)((w >> 23) & 3);
        int lr = atomicAdd(&lcnt[bl], 1);
        int rn = rn0 + bl;
        if (lr < 8) {
            elist8[(size_t)rn * 8 + lr] = (unsigned short)(w & 0xFFFF);
        } else if (lr < CAP) {
            ovf[(size_t)rn * OVF + (lr - 8)] = (unsigned short)(w & 0xFFFF);
        }
    }
    __syncthreads();
    if (tid < 512) {
        int rn = rn0 + tid;
        if (rn < RN) {
            int c = lcnt[tid];
            cnt8[rn] = (unsigned char)((c > 255) ? 255 : c);
        }
    }
}

// ---------- aggregate: wave = node, 16-lane group g = relation g (MLP-4) ----------
// preload 8 indices as uint4 (== elist8[bucket]); 4 guarded gathers in flight;
// rare tail from overflow. xcat row = [mean_r0..mean_r3] (512 cols bf16)
__global__ __launch_bounds__(256) void k_agg(const unsigned short* __restrict__ Xb,
                                             const unsigned char* __restrict__ cnt8,
                                             const unsigned short* __restrict__ elist8,
                                             const unsigned short* __restrict__ ovf,
                                             unsigned short* __restrict__ xcat) {
    int node = blockIdx.x * 4 + (threadIdx.x >> 6);
    int lane = threadIdx.x & 63;
    const int g = lane >> 4;     // relation
    const int t = lane & 15;     // lane-in-group: owns cols t*8..t*8+7 of that relation

    int bucket = (node << 2) | g;
    int c = cnt8[bucket];
    c = (c > CAP) ? CAP : c;
    uint4 e8 = *(const uint4*)(elist8 + (size_t)bucket * 8);   // entries 0..7

    int i0 = e8.x & 0xFFFF, i1 = e8.x >> 16;
    int i2 = e8.y & 0xFFFF, i3 = e8.y >> 16;
    int i4 = e8.z & 0xFFFF, i5 = e8.z >> 16;
    int i6 = e8.w & 0xFFFF, i7 = e8.w >> 16;

    const size_t toff = (size_t)(t * 8);
    const uint4 z = {0, 0, 0, 0};
    f32x2 A0[4] = {}, A1[4] = {}, A2[4] = {}, A3[4] = {};

    // chunk 0: edges 0..3, 4 loads in flight
    {
        uint4 d0 = z, d1 = z, d2 = z, d3 = z;
        if (c > 0) d0 = *(const uint4*)(Xb + (size_t)i0 * DIM + toff);
        if (c > 1) d1 = *(const uint4*)(Xb + (size_t)i1 * DIM + toff);
        if (c > 2) d2 = *(const uint4*)(Xb + (size_t)i2 * DIM + toff);
        if (c > 3) d3 = *(const uint4*)(Xb + (size_t)i3 * DIM + toff);
        acc_row(A0, d0); acc_row(A1, d1); acc_row(A2, d2); acc_row(A3, d3);
    }
    // chunk 1: edges 4..7
    if (c > 4) {
        uint4 d0 = z, d1 = z, d2 = z, d3 = z;
        d0 = *(const uint4*)(Xb + (size_t)i4 * DIM + toff);
        if (c > 5) d1 = *(const uint4*)(Xb + (size_t)i5 * DIM + toff);
        if (c > 6) d2 = *(const uint4*)(Xb + (size_t)i6 * DIM + toff);
        if (c > 7) d3 = *(const uint4*)(Xb + (size_t)i7 * DIM + toff);
        acc_row(A0, d0); acc_row(A1, d1); acc_row(A2, d2); acc_row(A3, d3);
    }
    // rare tail (P(c>8) ~ 2%) from overflow region
    for (int j = 8; j < c; ++j) {
        int s = ovf[(size_t)bucket * OVF + (j - 8)];
        uint4 d = *(const uint4*)(Xb + (size_t)s * DIM + toff);
        acc_row(A0, d);
    }
#pragma unroll
    for (int k = 0; k < 4; k++) {
        pk_add(A0[k], A1[k]);
        pk_add(A2[k], A3[k]);
        pk_add(A0[k], A2[k]);
    }

    float inv = 1.0f / fmaxf((float)c, 1.0f);
    u32x4 o;
    o.x = cvt_pk_bf16(A0[0][0] * inv, A0[0][1] * inv);
    o.y = cvt_pk_bf16(A0[1][0] * inv, A0[1][1] * inv);
    o.z = cvt_pk_bf16(A0[2][0] * inv, A0[2][1] * inv);
    o.w = cvt_pk_bf16(A0[3][0] * inv, A0[3][1] * inv);
    *(u32x4*)(xcat + (size_t)node * 512 + g * 128 + t * 8) = o;
}

// ---------- GEMM: Y[M,128] = [Xself | xcat][M,640](bf16) @ wcatT[128][640](bf16) ----------
// BM=64, BN=128, BK=64; 4 waves (2x2), each wave 32x64 out; 16x16x32 MFMA.
// A K-tiles 0..1 staged from Xself (stride 256B), 2..9 from xcat (stride 1024B).
__global__ __launch_bounds__(256) void k_gemm(const unsigned short* __restrict__ Xself,
                                              const unsigned short* __restrict__ Xagg,
                                              const unsigned short* __restrict__ Bt,
                                              const float* __restrict__ bias,
                                              void* __restrict__ Yv, int Mout,
                                              int relu, int obf16) {
    __shared__ unsigned short sA[64 * 64];    // [row][64 k] bf16, 16B-chunk XOR swizzled
    __shared__ unsigned short sB[128 * 64];   // [n][64 k]

    const int tid = threadIdx.x;
    const int lane = tid & 63;
    const int wid = tid >> 6;
    const int wm = wid >> 1, wn = wid & 1;
    const int m0 = blockIdx.x * 64;

    f32x4 acc[2][4] = {};

    const char* Bbase = (const char*)Bt;

    for (int kt = 0; kt < 10; ++kt) {
        const char* Asrc;
        size_t rstride;
        if (kt < 2) {
            Asrc = (const char*)Xself + (size_t)m0 * 256 + kt * 128;
            rstride = 256;
        } else {
            Asrc = (const char*)Xagg + (size_t)m0 * 1024 + (kt - 2) * 128;
            rstride = 1024;
        }
#pragma unroll
        for (int i = 0; i < 2; i++) {
            int chunk = i * 256 + tid;
            int row = chunk >> 3, cst = chunk & 7;
            int clog = cst ^ (row & 7);
            gload_lds16(Asrc + (size_t)row * rstride + clog * 16,
                        (char*)sA + (size_t)(chunk - lane) * 16);
        }
#pragma unroll
        for (int i = 0; i < 4; i++) {
            int chunk = i * 256 + tid;
            int row = chunk >> 3, cst = chunk & 7;
            int clog = cst ^ (row & 7);
            gload_lds16(Bbase + (size_t)row * 1280 + kt * 128 + clog * 16,
                        (char*)sB + (size_t)(chunk - lane) * 16);
        }
        __syncthreads();
#pragma unroll
        for (int ki = 0; ki < 2; ki++) {
            bf16x8 a[2], b[4];
#pragma unroll
            for (int mi = 0; mi < 2; mi++) {
                int row = wm * 32 + mi * 16 + (lane & 15);
                int c = ki * 4 + (lane >> 4);
                a[mi] = *(const bf16x8*)((const char*)sA + row * 128 + ((c ^ (row & 7)) << 4));
            }
#pragma unroll
            for (int ni = 0; ni < 4; ni++) {
                int row = wn * 64 + ni * 16 + (lane & 15);
                int c = ki * 4 + (lane >> 4);
                b[ni] = *(const bf16x8*)((const char*)sB + row * 128 + ((c ^ (row & 7)) << 4));
            }
#pragma unroll
            for (int mi = 0; mi < 2; mi++)
#pragma unroll
                for (int ni = 0; ni < 4; ni++)
                    acc[mi][ni] = __builtin_amdgcn_mfma_f32_16x16x32_bf16(a[mi], b[ni], acc[mi][ni], 0, 0, 0);
        }
        __syncthreads();
    }
#pragma unroll
    for (int mi = 0; mi < 2; mi++) {
#pragma unroll
        for (int ni = 0; ni < 4; ni++) {
            int col = wn * 64 + ni * 16 + (lane & 15);
            float bv = bias[col];
#pragma unroll
            for (int q = 0; q < 4; q++) {
                int row = m0 + wm * 32 + mi * 16 + (lane >> 4) * 4 + q;
                if (row < Mout) {
                    float v = acc[mi][ni][q] + bv;
                    if (relu) v = fmaxf(v, 0.f);
                    if (obf16)
                        ((unsigned short*)Yv)[(size_t)row * DIM + col] = f2bf(v);
                    else
                        ((float*)Yv)[(size_t)row * DIM + col] = v;
                }
            }
        }
    }
}

extern "C" void kernel_launch(void* const* d_in, const int* in_sizes, int n_in,
                              void* d_out, int out_size, void* d_ws, size_t ws_size,
                              hipStream_t stream) {
    const float* x = (const float*)d_in[0];
    const int* ei = (const int*)d_in[1];      // [2,E]: src = ei, dst = ei+E
    const int* et = (const int*)d_in[2];      // [E]
    const float* weights = (const float*)d_in[3];  // [L,R,D,D]
    const float* roots = (const float*)d_in[4];    // [L,D,D]
    const float* biases = (const float*)d_in[5];   // [L,D]
    float* out = (float*)d_out;

    const int* src = ei;
    const int* dst = ei + N_EDGES;

    // workspace layout (~95 MB)
    unsigned* gbincnt = (unsigned*)d_ws;                          // 512 u32
    unsigned* binbuf = gbincnt + 512;                             // NBIN*BINCAP u32 = 4.8 MB
    unsigned char* cnt8 = (unsigned char*)(binbuf + (size_t)NBIN * BINCAP);  // 200192 B
    unsigned short* elist8 = (unsigned short*)(cnt8 + 200192);    // RN*8 u16 = 3.2 MB
    unsigned short* ovf = elist8 + (size_t)RN * 8;                // RN*OVF u16 = 9.6 MB
    unsigned short* wcatT = ovf + (size_t)RN * OVF;               // 2*128*640
    unsigned short* xcat = wcatT + 2 * 128 * 640;                 // NPAD*512 bf16 = 51.2 MB
    unsigned short* xb = xcat + (size_t)NPAD * 512;               // NPAD*128 bf16
    unsigned short* hb = xb + (size_t)NPAD * 128;                 // NPAD*128 bf16

    k_zero<<<1, 512, 0, stream>>>(gbincnt);

    k_prepA<<<PREPA_B, 1024, 0, stream>>>(et, dst, src, gbincnt, binbuf, x, xb,
                                          weights, roots, wcatT);
    k_fine<<<NBIN, 1024, 0, stream>>>(gbincnt, binbuf, cnt8, elist8, ovf);

    // layer 0: xb -> hb (ReLU, bf16 out)
    k_agg<<<N_NODES / 4, 256, 0, stream>>>(xb, cnt8, elist8, ovf, xcat);
    k_gemm<<<NPAD / 64, 256, 0, stream>>>(xb, xcat, wcatT, biases, hb, N_NODES, 1, 1);
    // layer 1: hb -> out (no ReLU, fp32 out)
    k_agg<<<N_NODES / 4, 256, 0, stream>>>(hb, cnt8, elist8, ovf, xcat);
    k_gemm<<<NPAD / 64, 256, 0, stream>>>(hb, xcat, wcatT + 128 * 640, biases + DIM, out, N_NODES, 0, 0);
}